// Round 1
// baseline (153.018 us; speedup 1.0000x reference)
//
#include <hip/hip_runtime.h>
#include <math.h>

#define IN_NODES 1152
#define OUT_NODES 10
#define IN_DIM 8
#define OUT_DIM 16
#define BATCH 256
#define CHUNKS 64
#define I_PER_CHUNK 18   // 1152 / 64
#define BTILES 4
#define BTILE 64

// ---------------------------------------------------------------------------
// xr[i, b, k] = x[b, i, k]   (one-time transpose for coalesced per-i access)
// ---------------------------------------------------------------------------
__global__ __launch_bounds__(256) void k_transpose(const float* __restrict__ x,
                                                   float* __restrict__ xr) {
    int i = blockIdx.x;   // 0..1151
    int b = threadIdx.x;  // 0..255
    const float* src = x + (size_t)b * (IN_NODES * IN_DIM) + (size_t)i * IN_DIM;
    float4 a0 = ((const float4*)src)[0];
    float4 a1 = ((const float4*)src)[1];
    float* dst = xr + (size_t)i * (BATCH * IN_DIM) + (size_t)b * IN_DIM;
    ((float4*)dst)[0] = a0;
    ((float4*)dst)[1] = a1;
}

// ---------------------------------------------------------------------------
// b_logits = 0, c = softmax(0) = 1/OUT_NODES
// ---------------------------------------------------------------------------
__global__ void k_init(float* __restrict__ blog, float* __restrict__ cbuf) {
    int t = blockIdx.x * 256 + threadIdx.x;
    if (t < IN_NODES * OUT_NODES) {
        blog[t] = 0.0f;
        cbuf[t] = 1.0f / OUT_NODES;
    }
}

// ---------------------------------------------------------------------------
// Split-K GEMM:  part[chunk][j][b][d] = sum_{i in chunk} c[i,j] * (W[i,j,d,:].x[b,i,:])
// grid = (CHUNKS, BTILES), block = 256.  thread: d = tid&15, bq = tid>>4 (4 b's each)
// ---------------------------------------------------------------------------
__global__ __launch_bounds__(256) void k_gemm1(const float* __restrict__ W,
                                               const float* __restrict__ xr,
                                               const float* __restrict__ cbuf,
                                               float* __restrict__ part) {
    __shared__ float w_lds[OUT_NODES * OUT_DIM * 12];  // 1920 floats, rows padded 8->12
    __shared__ float x_lds[BTILE * 12];                // 768 floats, rows padded 8->12
    __shared__ float c_lds[OUT_NODES];

    const int chunk = blockIdx.x;
    const int btile = blockIdx.y;
    const int tid = threadIdx.x;
    const int d = tid & 15;
    const int bq = tid >> 4;  // 0..15

    float acc[OUT_NODES][4];
#pragma unroll
    for (int j = 0; j < OUT_NODES; ++j)
#pragma unroll
        for (int bb = 0; bb < 4; ++bb) acc[j][bb] = 0.0f;

    const int i0 = chunk * I_PER_CHUNK;
    for (int ii = 0; ii < I_PER_CHUNK; ++ii) {
        const int i = i0 + ii;
        // stage W[i,:,:,:] (1280 floats) into padded LDS
#pragma unroll
        for (int r = 0; r < 5; ++r) {
            int t = tid + r * 256;
            w_lds[(t >> 3) * 12 + (t & 7)] = W[(size_t)i * 1280 + t];
        }
        // stage x_i for this btile (512 floats)
#pragma unroll
        for (int r = 0; r < 2; ++r) {
            int t = tid + r * 256;
            x_lds[(t >> 3) * 12 + (t & 7)] =
                xr[(size_t)i * (BATCH * IN_DIM) + (size_t)btile * (BTILE * IN_DIM) + t];
        }
        if (tid < OUT_NODES) c_lds[tid] = cbuf[i * OUT_NODES + tid];
        __syncthreads();

        // this thread's 4 b-rows of x into registers
        float xv[4][8];
#pragma unroll
        for (int bb = 0; bb < 4; ++bb) {
            float4 xa = *(const float4*)&x_lds[(bq * 4 + bb) * 12];
            float4 xb = *(const float4*)&x_lds[(bq * 4 + bb) * 12 + 4];
            xv[bb][0] = xa.x; xv[bb][1] = xa.y; xv[bb][2] = xa.z; xv[bb][3] = xa.w;
            xv[bb][4] = xb.x; xv[bb][5] = xb.y; xv[bb][6] = xb.z; xv[bb][7] = xb.w;
        }

#pragma unroll
        for (int j = 0; j < OUT_NODES; ++j) {
            const int row = (j * 16 + d) * 12;
            float4 w0 = *(const float4*)&w_lds[row];
            float4 w1 = *(const float4*)&w_lds[row + 4];
            float cij = c_lds[j];
#pragma unroll
            for (int bb = 0; bb < 4; ++bb) {
                float dot = w0.x * xv[bb][0] + w0.y * xv[bb][1] + w0.z * xv[bb][2] +
                            w0.w * xv[bb][3] + w1.x * xv[bb][4] + w1.y * xv[bb][5] +
                            w1.z * xv[bb][6] + w1.w * xv[bb][7];
                acc[j][bb] = fmaf(cij, dot, acc[j][bb]);
            }
        }
        __syncthreads();
    }

    // write partials: part[chunk][j][b_global][d]
    const size_t base = (size_t)chunk * OUT_NODES * BATCH * OUT_DIM;
#pragma unroll
    for (int j = 0; j < OUT_NODES; ++j)
#pragma unroll
        for (int bb = 0; bb < 4; ++bb) {
            int bg = btile * BTILE + bq * 4 + bb;
            part[base + ((size_t)j * BATCH + bg) * OUT_DIM + d] = acc[j][bb];
        }
}

// ---------------------------------------------------------------------------
// Reduce partials over chunks + squash.  grid = (OUT_NODES, BTILES), block 256.
// thread: dq = tid&3 (4 d's), bl = tid>>2 (64 b's per block)
// ---------------------------------------------------------------------------
__global__ __launch_bounds__(256) void k_reduce_squash(const float* __restrict__ part,
                                                       float* __restrict__ v,
                                                       float* __restrict__ out,
                                                       int write_out) {
    const int j = blockIdx.x;
    const int tid = threadIdx.x;
    const int dq = tid & 3;
    const int bl = tid >> 2;
    const int b = blockIdx.y * BTILE + bl;

    float4 s = make_float4(0.f, 0.f, 0.f, 0.f);
    for (int chunk = 0; chunk < CHUNKS; ++chunk) {
        float4 p = *(const float4*)&part[(((size_t)chunk * OUT_NODES + j) * BATCH + b) *
                                             OUT_DIM + dq * 4];
        s.x += p.x; s.y += p.y; s.z += p.z; s.w += p.w;
    }
    float sq = s.x * s.x + s.y * s.y + s.z * s.z + s.w * s.w;
    sq += __shfl_xor(sq, 1);
    sq += __shfl_xor(sq, 2);
    float scale = sq / ((1.0f + sq) * sqrtf(sq));
    float4 vv = make_float4(s.x * scale, s.y * scale, s.z * scale, s.w * scale);
    *(float4*)&v[((size_t)j * BATCH + b) * OUT_DIM + dq * 4] = vv;
    if (write_out) {
        *(float4*)&out[(size_t)b * (OUT_NODES * OUT_DIM) + j * OUT_DIM + dq * 4] = vv;
    }
}

// ---------------------------------------------------------------------------
// Agreement + b-logit update + softmax -> new c.  grid = IN_NODES, block 256.
// a[i,j] = sum_{k,d} W[i,j,d,k] * (sum_b x[b,i,k] * v[j,b,d])
// ---------------------------------------------------------------------------
__global__ __launch_bounds__(256) void k_agree(const float* __restrict__ W,
                                               const float* __restrict__ xr,
                                               const float* __restrict__ v,
                                               float* __restrict__ blog,
                                               float* __restrict__ cbuf) {
    __shared__ float x_lds[BATCH * IN_DIM];  // 2048 floats
    __shared__ float red[OUT_NODES * OUT_DIM];
    __shared__ float bshare[OUT_NODES];

    const int i = blockIdx.x;
    const int tid = threadIdx.x;

#pragma unroll
    for (int r = 0; r < 8; ++r)
        x_lds[tid + r * 256] = xr[(size_t)i * (BATCH * IN_DIM) + tid + r * 256];
    __syncthreads();

    if (tid < OUT_NODES * OUT_DIM) {
        const int j = tid >> 4;
        const int d = tid & 15;
        float acck[8] = {0.f, 0.f, 0.f, 0.f, 0.f, 0.f, 0.f, 0.f};
        const float* vp = v + (size_t)j * BATCH * OUT_DIM + d;
#pragma unroll 4
        for (int b = 0; b < BATCH; ++b) {
            float vb = vp[(size_t)b * OUT_DIM];
            float4 xa = *(const float4*)&x_lds[b * 8];
            float4 xb = *(const float4*)&x_lds[b * 8 + 4];
            acck[0] = fmaf(xa.x, vb, acck[0]);
            acck[1] = fmaf(xa.y, vb, acck[1]);
            acck[2] = fmaf(xa.z, vb, acck[2]);
            acck[3] = fmaf(xa.w, vb, acck[3]);
            acck[4] = fmaf(xb.x, vb, acck[4]);
            acck[5] = fmaf(xb.y, vb, acck[5]);
            acck[6] = fmaf(xb.z, vb, acck[6]);
            acck[7] = fmaf(xb.w, vb, acck[7]);
        }
        const float4* wp = (const float4*)&W[(size_t)i * 1280 + (j * 16 + d) * 8];
        float4 w0 = wp[0], w1 = wp[1];
        float pa = w0.x * acck[0] + w0.y * acck[1] + w0.z * acck[2] + w0.w * acck[3] +
                   w1.x * acck[4] + w1.y * acck[5] + w1.z * acck[6] + w1.w * acck[7];
        red[tid] = pa;
    }
    __syncthreads();

    if (tid < OUT_NODES) {
        float a = 0.f;
#pragma unroll
        for (int dd = 0; dd < OUT_DIM; ++dd) a += red[tid * OUT_DIM + dd];
        float bn = blog[i * OUT_NODES + tid] + a * (1.0f / BATCH);
        blog[i * OUT_NODES + tid] = bn;
        bshare[tid] = bn;
    }
    __syncthreads();

    if (tid < OUT_NODES) {
        float m = bshare[0];
#pragma unroll
        for (int jj = 1; jj < OUT_NODES; ++jj) m = fmaxf(m, bshare[jj]);
        float ssum = 0.f;
#pragma unroll
        for (int jj = 0; jj < OUT_NODES; ++jj) ssum += __expf(bshare[jj] - m);
        cbuf[i * OUT_NODES + tid] = __expf(bshare[tid] - m) / ssum;
    }
}

// ---------------------------------------------------------------------------
extern "C" void kernel_launch(void* const* d_in, const int* in_sizes, int n_in,
                              void* d_out, int out_size, void* d_ws, size_t ws_size,
                              hipStream_t stream) {
    const float* x = (const float*)d_in[0];  // [256,1152,8]
    const float* W = (const float*)d_in[1];  // [1152,10,16,8]
    float* out = (float*)d_out;              // [256,10,16,1]
    float* ws = (float*)d_ws;

    float* xr   = ws;                                              // 2,359,296 f
    float* part = xr + (size_t)IN_NODES * BATCH * IN_DIM;          // 2,621,440 f
    float* v    = part + (size_t)CHUNKS * OUT_NODES * BATCH * OUT_DIM;  // 40,960 f
    float* blog = v + (size_t)OUT_NODES * BATCH * OUT_DIM;         // 11,520 f
    float* cbuf = blog + (size_t)IN_NODES * OUT_NODES;             // 11,520 f
    // total ~20.2 MB of ws

    k_transpose<<<IN_NODES, BATCH, 0, stream>>>(x, xr);
    k_init<<<(IN_NODES * OUT_NODES + 255) / 256, 256, 0, stream>>>(blog, cbuf);

    for (int it = 0; it < 3; ++it) {
        k_gemm1<<<dim3(CHUNKS, BTILES), 256, 0, stream>>>(W, xr, cbuf, part);
        k_reduce_squash<<<dim3(OUT_NODES, BTILES), 256, 0, stream>>>(part, v, out,
                                                                     it == 2 ? 1 : 0);
        if (it < 2) k_agree<<<IN_NODES, 256, 0, stream>>>(W, xr, v, blog, cbuf);
    }
}